// Round 1
// baseline (479.987 us; speedup 1.0000x reference)
//
#include <hip/hip_runtime.h>
#include <math.h>

#define B_   32
#define NB_  1024
#define H_   768
#define K_   384   // H/2
#define C_   64

// ---------------------------------------------------------------------------
// Kernel 1: gate[b,n] = W2 . tanh(x[b,n,:] @ W1 + b1) + b2
// One block = 16 rows of the (B*NB, H) matrix. 192 threads; thread t computes
// output columns t and t+192 of the first layer for all 16 rows.
// x tile staged in LDS; read back as float4 broadcasts (all lanes same addr =
// conflict-free). W1 streamed from L2 (1.18 MB, fully L2-resident).
// Per 4-h chunk/thread: 16 ds_read_b128 + 8 global loads + 128 FMA -> VALU-bound.
// ---------------------------------------------------------------------------
__global__ __launch_bounds__(192) void gate_kernel(
    const float* __restrict__ tokens, const float* __restrict__ W1,
    const float* __restrict__ b1, const float* __restrict__ W2,
    const float* __restrict__ b2, float* __restrict__ gate)
{
    __shared__ float smem[16 * H_];          // 48 KiB; reused for reduction
    float (*xs)[H_] = (float (*)[H_])smem;

    const int tid  = threadIdx.x;
    const int row0 = blockIdx.x * 16;        // first of 16 rows (flat b*NB+n)

    // stage 16x768 fp32 tile (float4, coalesced)
    {
        const float4* s4 = (const float4*)(tokens + (size_t)row0 * H_);
        float4* d4 = (float4*)smem;
        for (int i = tid; i < 16 * H_ / 4; i += 192) d4[i] = s4[i];
    }
    __syncthreads();

    const int k0 = tid, k1 = tid + 192;
    float acc0[16], acc1[16];
#pragma unroll
    for (int r = 0; r < 16; ++r) { acc0[r] = 0.f; acc1[r] = 0.f; }

    for (int h = 0; h < H_; h += 4) {
        float4 xv[16];
#pragma unroll
        for (int r = 0; r < 16; ++r) xv[r] = *(const float4*)&xs[r][h];
        const float wa0 = W1[(h + 0) * K_ + k0];
        const float wa1 = W1[(h + 1) * K_ + k0];
        const float wa2 = W1[(h + 2) * K_ + k0];
        const float wa3 = W1[(h + 3) * K_ + k0];
        const float wb0 = W1[(h + 0) * K_ + k1];
        const float wb1 = W1[(h + 1) * K_ + k1];
        const float wb2 = W1[(h + 2) * K_ + k1];
        const float wb3 = W1[(h + 3) * K_ + k1];
#pragma unroll
        for (int r = 0; r < 16; ++r) {
            acc0[r] += xv[r].x * wa0 + xv[r].y * wa1 + xv[r].z * wa2 + xv[r].w * wa3;
            acc1[r] += xv[r].x * wb0 + xv[r].y * wb1 + xv[r].z * wb2 + xv[r].w * wb3;
        }
    }

    const float bb1a = b1[k0], bb1b = b1[k1];
    const float w2a  = W2[k0], w2b  = W2[k1];

    __syncthreads();                         // done reading xs; reuse smem
    float* ph = smem;                        // [16][193] padded partials
#pragma unroll
    for (int r = 0; r < 16; ++r)
        ph[r * 193 + tid] = tanhf(acc0[r] + bb1a) * w2a
                          + tanhf(acc1[r] + bb1b) * w2b;
    __syncthreads();

    if (tid < 16) {
        float s = b2[0];
        for (int j = 0; j < 192; ++j) s += ph[tid * 193 + j];
        gate[row0 + tid] = s;
    }
}

// ---------------------------------------------------------------------------
// Kernel 2: per (b,c) masked softmax over NB blocks + weighted token sum.
// One block per (b,c); weights built in LDS; accumulation is uniform-branch
// (w broadcast from LDS) with coalesced token reads (thread t owns dims
// t, t+256, t+512).
// ---------------------------------------------------------------------------
__global__ __launch_bounds__(256) void agg_kernel(
    const float* __restrict__ tokens, const int* __restrict__ active,
    const int* __restrict__ cmap, const float* __restrict__ gate,
    float* __restrict__ out_tok, float* __restrict__ out_act)
{
    __shared__ float wls[NB_];
    __shared__ float red[256];
    const int b   = blockIdx.x >> 6;   // / C_
    const int c   = blockIdx.x & 63;   // % C_
    const int tid = threadIdx.x;

    // phase A: masked gate + max
    float lmax = -INFINITY;
    for (int n = tid; n < NB_; n += 256) {
        const bool msk = (active[b * NB_ + n] != 0) && (cmap[n] == c);
        const float g  = msk ? gate[b * NB_ + n] : -INFINITY;
        wls[n] = g;
        lmax = fmaxf(lmax, g);
    }
    red[tid] = lmax;
    __syncthreads();
    for (int s = 128; s > 0; s >>= 1) {
        if (tid < s) red[tid] = fmaxf(red[tid], red[tid + s]);
        __syncthreads();
    }
    const float m = red[0];
    __syncthreads();
    const float msafe = (m > -INFINITY) ? m : 0.f;

    // phase B: exp + sum
    float lsum = 0.f;
    for (int n = tid; n < NB_; n += 256) {
        const float g = wls[n];
        const float e = (g > -INFINITY) ? expf(g - msafe) : 0.f;
        wls[n] = e;
        lsum += e;
    }
    red[tid] = lsum;
    __syncthreads();
    for (int s = 128; s > 0; s >>= 1) {
        if (tid < s) red[tid] += red[tid + s];
        __syncthreads();
    }
    const float ssum = red[0];
    const float inv  = (ssum > 0.f) ? 1.f / ssum : 0.f;
    __syncthreads();
    for (int n = tid; n < NB_; n += 256) wls[n] *= inv;
    __syncthreads();

    // phase C: weighted accumulation (uniform branch per n)
    float a0 = 0.f, a1 = 0.f, a2 = 0.f;
    const float* tb = tokens + (size_t)b * NB_ * H_;
    for (int n = 0; n < NB_; ++n) {
        const float w = wls[n];
        if (w != 0.f) {
            const float* t = tb + (size_t)n * H_;
            a0 += w * t[tid];
            a1 += w * t[tid + 256];
            a2 += w * t[tid + 512];
        }
    }
    float* o = out_tok + ((size_t)(b * C_ + c)) * H_;
    o[tid]       = a0;
    o[tid + 256] = a1;
    o[tid + 512] = a2;
    if (tid == 0) out_act[b * C_ + c] = (m > -INFINITY) ? 1.f : 0.f;
}

// ---------------------------------------------------------------------------
extern "C" void kernel_launch(void* const* d_in, const int* in_sizes, int n_in,
                              void* d_out, int out_size, void* d_ws, size_t ws_size,
                              hipStream_t stream)
{
    const float* tokens = (const float*)d_in[0];   // (B, NB, H) fp32
    const int*   active = (const int*)  d_in[1];   // (B, NB) int (bool)
    const int*   cmap   = (const int*)  d_in[2];   // (NB,) int
    const float* W1     = (const float*)d_in[3];   // (H, H/2)
    const float* b1     = (const float*)d_in[4];   // (H/2,)
    const float* W2     = (const float*)d_in[5];   // (H/2, 1)
    const float* b2     = (const float*)d_in[6];   // (1,)

    float* out      = (float*)d_out;                       // tokens then active
    float* out_act  = out + (size_t)B_ * C_ * H_;
    float* gate_ws  = (float*)d_ws;                        // B*NB floats

    gate_kernel<<<(B_ * NB_) / 16, 192, 0, stream>>>(tokens, W1, b1, W2, b2, gate_ws);
    agg_kernel<<<B_ * C_, 256, 0, stream>>>(tokens, active, cmap, gate_ws, out, out_act);
}

// Round 2
// 66.689 us; speedup vs baseline: 7.1974x; 7.1974x over previous
//
#include <hip/hip_runtime.h>
#include <math.h>

#define B_   32
#define NB_  1024
#define H_   768
#define K_   384
#define C_   64

#define ROWS_   128              // rows per gate block
#define NSTEP_  (H_ / 32)        // 24 K-steps of 32
#define NT_     (K_ / 16)        // 24 n-tiles of 16

typedef __attribute__((ext_vector_type(8))) short  bf16x8;
typedef __attribute__((ext_vector_type(4))) float  f32x4;

__device__ __forceinline__ short f2bf(float f) {   // RNE fp32 -> bf16 bits
    unsigned u = __float_as_uint(f);
    unsigned r = (u + 0x7fffu + ((u >> 16) & 1u)) >> 16;
    return (short)r;
}

// ---------------------------------------------------------------------------
// Prep: W1 (768x384 fp32, n contiguous) -> bf16 swizzled into exact MFMA
// B-fragment order: frag (s,t): lane l, elem i = W1[s*32+(l>>4)*8+i][t*16+(l&15)]
// stored at ((s*24+t)*64 + l)*8 + i   (bf16 elements).
// ---------------------------------------------------------------------------
__global__ __launch_bounds__(256) void prep_w1(const float* __restrict__ W1,
                                               short* __restrict__ swz)
{
    int idx = blockIdx.x * 256 + threadIdx.x;        // 294912 = 768*384
    int k = idx / K_, n = idx % K_;
    float v = W1[idx];
    int s = k >> 5, g = (k >> 3) & 3, i = k & 7;
    int t = n >> 4, nn = n & 15;
    swz[((s * 24 + t) * 512) + (g * 16 + nn) * 8 + i] = f2bf(v);
}

// ---------------------------------------------------------------------------
// Gate MLP via MFMA. Block: 512 thr (8 waves) = 128 rows x 384 cols.
// Wave w: all 128 rows x cols [w*48, w*48+48)  -> acc[8][3] f32x4.
// Double-buffered LDS; A converted fp32->bf16 on staging; B copied from
// pre-swizzled global (contiguous, L2-resident).
// ---------------------------------------------------------------------------
__global__ __launch_bounds__(512, 2) void gate_kernel(
    const float* __restrict__ tokens, const short* __restrict__ swz,
    const float* __restrict__ b1, const float* __restrict__ W2,
    const float* __restrict__ b2, float* __restrict__ gate)
{
    __shared__ short As[2][8 * 512];    //  8 KiB/buf: frag f, lane l -> 8 bf16
    __shared__ short Bs[2][24 * 512];   // 24 KiB/buf: tile t, lane l -> 8 bf16
    __shared__ float red[8][128];       // epilogue partials

    const int tid  = threadIdx.x;
    const int lane = tid & 63;
    const int w    = tid >> 6;          // wave 0..7
    const int row0 = blockIdx.x * ROWS_;

    // per-thread staging geometry (constant across K-steps)
    const int arow = tid >> 2;          // 0..127
    const int akc  = tid & 3;           // which 8-k chunk of 32
    const size_t agbase = (size_t)(row0 + arow) * H_ + akc * 8;
    const int    aoff   = (arow >> 4) * 512 + (akc * 16 + (arow & 15)) * 8;

    f32x4 acc[8][3];
#pragma unroll
    for (int f = 0; f < 8; ++f)
#pragma unroll
        for (int j = 0; j < 3; ++j) acc[f][j] = (f32x4){0.f, 0.f, 0.f, 0.f};

    // ---- prologue: stage s = 0 into buf 0
    {
        float4 pa0 = *(const float4*)(tokens + agbase);
        float4 pa1 = *(const float4*)(tokens + agbase + 4);
        float4 pb0 = *(const float4*)((const char*)swz + 0 * 8192 + tid * 16);
        float4 pb1 = *(const float4*)((const char*)swz + 1 * 8192 + tid * 16);
        float4 pb2 = *(const float4*)((const char*)swz + 2 * 8192 + tid * 16);
        bf16x8 av = { f2bf(pa0.x), f2bf(pa0.y), f2bf(pa0.z), f2bf(pa0.w),
                      f2bf(pa1.x), f2bf(pa1.y), f2bf(pa1.z), f2bf(pa1.w) };
        *(bf16x8*)&As[0][aoff] = av;
        *(float4*)&Bs[0][0 * 4096 + tid * 8] = pb0;
        *(float4*)&Bs[0][1 * 4096 + tid * 8] = pb1;
        *(float4*)&Bs[0][2 * 4096 + tid * 8] = pb2;
    }
    __syncthreads();

    int buf = 0;
    for (int s = 0; s < NSTEP_; ++s) {
        float4 pa0, pa1, pb0, pb1, pb2;
        if (s < NSTEP_ - 1) {           // issue next-tile loads early (T14)
            const size_t ga = agbase + (size_t)(s + 1) * 32;
            pa0 = *(const float4*)(tokens + ga);
            pa1 = *(const float4*)(tokens + ga + 4);
            const char* gb = (const char*)swz + (size_t)(s + 1) * 24576;
            pb0 = *(const float4*)(gb + 0 * 8192 + tid * 16);
            pb1 = *(const float4*)(gb + 1 * 8192 + tid * 16);
            pb2 = *(const float4*)(gb + 2 * 8192 + tid * 16);
        }

        // compute on buf
        bf16x8 af[8];
#pragma unroll
        for (int f = 0; f < 8; ++f)
            af[f] = *(bf16x8*)&As[buf][f * 512 + lane * 8];
#pragma unroll
        for (int j = 0; j < 3; ++j) {
            bf16x8 bv = *(bf16x8*)&Bs[buf][(w * 3 + j) * 512 + lane * 8];
#pragma unroll
            for (int f = 0; f < 8; ++f)
                acc[f][j] = __builtin_amdgcn_mfma_f32_16x16x32_bf16(
                                af[f], bv, acc[f][j], 0, 0, 0);
        }

        if (s < NSTEP_ - 1) {           // late write into the other buffer
            bf16x8 av = { f2bf(pa0.x), f2bf(pa0.y), f2bf(pa0.z), f2bf(pa0.w),
                          f2bf(pa1.x), f2bf(pa1.y), f2bf(pa1.z), f2bf(pa1.w) };
            *(bf16x8*)&As[buf ^ 1][aoff] = av;
            *(float4*)&Bs[buf ^ 1][0 * 4096 + tid * 8] = pb0;
            *(float4*)&Bs[buf ^ 1][1 * 4096 + tid * 8] = pb1;
            *(float4*)&Bs[buf ^ 1][2 * 4096 + tid * 8] = pb2;
        }
        __syncthreads();
        buf ^= 1;
    }

    // ---- epilogue: gate[row] = b2 + sum_n tanh(h[row][n] + b1[n]) * W2[n]
    float ps[8][4];
#pragma unroll
    for (int f = 0; f < 8; ++f)
#pragma unroll
        for (int r = 0; r < 4; ++r) ps[f][r] = 0.f;

#pragma unroll
    for (int j = 0; j < 3; ++j) {
        const int n  = (w * 3 + j) * 16 + (lane & 15);
        const float bb = b1[n];
        const float ww = W2[n];
#pragma unroll
        for (int f = 0; f < 8; ++f)
#pragma unroll
            for (int r = 0; r < 4; ++r)
                ps[f][r] += tanhf(acc[f][j][r] + bb) * ww;
    }
    // reduce across the 16 lanes sharing a row (bits 0..3 of lane)
#pragma unroll
    for (int m = 1; m < 16; m <<= 1)
#pragma unroll
        for (int f = 0; f < 8; ++f)
#pragma unroll
            for (int r = 0; r < 4; ++r)
                ps[f][r] += __shfl_xor(ps[f][r], m, 64);

    if ((lane & 15) == 0) {
        const int rbase = (lane >> 4) * 4;
#pragma unroll
        for (int f = 0; f < 8; ++f)
#pragma unroll
            for (int r = 0; r < 4; ++r)
                red[w][f * 16 + rbase + r] = ps[f][r];
    }
    __syncthreads();
    if (tid < ROWS_) {
        float sgate = b2[0];
#pragma unroll
        for (int ww2 = 0; ww2 < 8; ++ww2) sgate += red[ww2][tid];
        gate[row0 + tid] = sgate;
    }
}

// ---------------------------------------------------------------------------
// Per-(b,c) masked softmax + weighted token sum. Deterministic ballot-based
// compaction so phase C only touches active blocks (~8 of 1024).
// ---------------------------------------------------------------------------
__global__ __launch_bounds__(256) void agg_kernel(
    const float* __restrict__ tokens, const int* __restrict__ active,
    const int* __restrict__ cmap, const float* __restrict__ gate,
    float* __restrict__ out_tok, float* __restrict__ out_act)
{
    __shared__ float wls[NB_];
    __shared__ float red[256];
    __shared__ int   idxs[NB_];
    __shared__ float wts[NB_];
    __shared__ int   gbase[17];

    const int b = blockIdx.x >> 6, c = blockIdx.x & 63;
    const int tid = threadIdx.x, lane = tid & 63, wid = tid >> 6;

    // phase A: masked gate + max
    float lmax = -INFINITY;
    for (int n = tid; n < NB_; n += 256) {
        const bool msk = (active[b * NB_ + n] != 0) && (cmap[n] == c);
        const float g  = msk ? gate[b * NB_ + n] : -INFINITY;
        wls[n] = g;
        lmax = fmaxf(lmax, g);
    }
    red[tid] = lmax; __syncthreads();
    for (int s = 128; s > 0; s >>= 1) {
        if (tid < s) red[tid] = fmaxf(red[tid], red[tid + s]);
        __syncthreads();
    }
    const float m = red[0]; __syncthreads();
    const float msafe = (m > -INFINITY) ? m : 0.f;

    // phase B: exp + sum
    float lsum = 0.f;
    for (int n = tid; n < NB_; n += 256) {
        const float g = wls[n];
        const float e = (g > -INFINITY) ? __expf(g - msafe) : 0.f;
        wls[n] = e; lsum += e;
    }
    red[tid] = lsum; __syncthreads();
    for (int s = 128; s > 0; s >>= 1) {
        if (tid < s) red[tid] += red[tid + s];
        __syncthreads();
    }
    const float ssum = red[0];
    const float inv  = (ssum > 0.f) ? 1.f / ssum : 0.f;
    __syncthreads();

    // deterministic compaction: group g = it*4+wid covers n = g*64+lane
#pragma unroll
    for (int it = 0; it < 4; ++it) {
        const int n = it * 256 + wid * 64 + lane;
        const unsigned long long mask = __ballot(wls[n] > 0.f);
        if (lane == 0) gbase[1 + it * 4 + wid] = __popcll(mask);
    }
    __syncthreads();
    if (tid == 0) {
        gbase[0] = 0;
        for (int i = 1; i <= 16; ++i) gbase[i] += gbase[i - 1];
    }
    __syncthreads();
#pragma unroll
    for (int it = 0; it < 4; ++it) {
        const int n = it * 256 + wid * 64 + lane;
        const float e = wls[n];
        const unsigned long long mask = __ballot(e > 0.f);
        if (e > 0.f) {
            const int pos = gbase[it * 4 + wid] +
                            __popcll(mask & ((1ull << lane) - 1ull));
            idxs[pos] = n;
            wts[pos]  = e * inv;
        }
    }
    __syncthreads();
    const int cnt = gbase[16];

    // phase C: weighted accumulation over the compacted list
    float a0 = 0.f, a1 = 0.f, a2 = 0.f;
    const float* tb = tokens + (size_t)b * NB_ * H_;
    for (int i = 0; i < cnt; ++i) {
        const float wv = wts[i];
        const float* t = tb + (size_t)idxs[i] * H_;
        a0 += wv * t[tid];
        a1 += wv * t[tid + 256];
        a2 += wv * t[tid + 512];
    }
    float* o = out_tok + ((size_t)(b * C_ + c)) * H_;
    o[tid]       = a0;
    o[tid + 256] = a1;
    o[tid + 512] = a2;
    if (tid == 0) out_act[b * C_ + c] = (m > -INFINITY) ? 1.f : 0.f;
}

// ---------------------------------------------------------------------------
extern "C" void kernel_launch(void* const* d_in, const int* in_sizes, int n_in,
                              void* d_out, int out_size, void* d_ws, size_t ws_size,
                              hipStream_t stream)
{
    const float* tokens = (const float*)d_in[0];
    const int*   active = (const int*)  d_in[1];
    const int*   cmap   = (const int*)  d_in[2];
    const float* W1     = (const float*)d_in[3];
    const float* b1     = (const float*)d_in[4];
    const float* W2     = (const float*)d_in[5];
    const float* b2     = (const float*)d_in[6];

    float* out      = (float*)d_out;
    float* out_act  = out + (size_t)B_ * C_ * H_;

    short* swz     = (short*)d_ws;                          // 589824 B
    float* gate_ws = (float*)((char*)d_ws + 589824);        // 131072 B

    prep_w1<<<(H_ * K_) / 256, 256, 0, stream>>>(W1, swz);
    gate_kernel<<<(B_ * NB_) / ROWS_, 512, 0, stream>>>(tokens, swz, b1, W2, b2, gate_ws);
    agg_kernel<<<B_ * C_, 256, 0, stream>>>(tokens, active, cmap, gate_ws, out, out_act);
}